// Round 3
// baseline (180.415 us; speedup 1.0000x reference)
//
#include <hip/hip_runtime.h>
#include <math.h>

#define GDIM 128
#define CDIM 32
#define EPSV 1e-8f
#define INV_SIGMA 10.0f
#define PAD 4   // row stride GDIM+PAD floats -> <=2-way LDS bank aliasing in scalar phases

__global__ __launch_bounds__(256) void nc_kernel(
    const float* __restrict__ x, const float* __restrict__ v,
    const int*   __restrict__ k, const float* __restrict__ X,
    float* __restrict__ out)
{
    const int i = blockIdx.x;
    const int t = threadIdx.x;

    __shared__ float sdel[CDIM][GDIM + PAD];  // 32 x 132 floats = 16.9 KB
    __shared__ float sx[GDIM];
    __shared__ float sv[GDIM];
    __shared__ int   sk[CDIM];
    __shared__ float stv[CDIM];
    __shared__ float s_vnorm;
    __shared__ float s_mean;
    __shared__ float s_acc[GDIM];
    __shared__ float s_sumd[GDIM];

    // ---- stage x, v rows and neighbor indices ----
    if (t < GDIM) {
        sx[t] = x[(size_t)i * GDIM + t];
        sv[t] = v[(size_t)i * GDIM + t];
    } else if (t < GDIM + CDIM) {
        sk[t - GDIM] = k[(size_t)i * CDIM + (t - GDIM)];
    }
    __syncthreads();

    // ---- gather X[k[c]] and form deltas into LDS (float4, coalesced) ----
    // 32 lanes per neighbor row (32 float4 = 128 floats), 8 rows per round, 4 rounds.
    {
        const int lane4 = (t & 31) * 4;
        const float4 xv = *reinterpret_cast<const float4*>(&sx[lane4]);
        #pragma unroll
        for (int r = 0; r < 4; ++r) {
            const int c = (t >> 5) + r * 8;
            const float4 Xv = *reinterpret_cast<const float4*>(
                &X[(size_t)sk[c] * GDIM + lane4]);
            float4 d;
            d.x = Xv.x - xv.x; d.y = Xv.y - xv.y;
            d.z = Xv.z - xv.z; d.w = Xv.w - xv.w;
            *reinterpret_cast<float4*>(&sdel[c][lane4]) = d;
        }
    }

    // ---- ||v|| by wave 0 (overlaps gather latency) ----
    if (t < 64) {
        float a = sv[t], b = sv[t + 64];
        float vn = a * a + b * b;
        #pragma unroll
        for (int off = 32; off; off >>= 1) vn += __shfl_xor(vn, off);
        if (t == 0) s_vnorm = sqrtf(vn);
    }
    __syncthreads();

    // ---- Phase A: per-neighbor dot(v,delta) and ||delta||^2 ----
    // 8 threads per neighbor c, strided scalar LDS reads (2-way bank alias, free).
    {
        const int c = t >> 3;
        const int l = t & 7;
        float num = 0.f, ss = 0.f;
        #pragma unroll
        for (int j = 0; j < 16; ++j) {
            const int g = l + 8 * j;
            const float d = sdel[c][g];
            num = fmaf(sv[g], d, num);
            ss  = fmaf(d, d, ss);
        }
        #pragma unroll
        for (int off = 4; off; off >>= 1) {
            num += __shfl_xor(num, off);
            ss  += __shfl_xor(ss, off);
        }
        if (l == 0) {
            const float dn = sqrtf(ss);
            const float cs = num / fmaxf(s_vnorm * dn, EPSV);
            stv[c] = expm1f(cs * INV_SIGMA);
        }
    }
    __syncthreads();

    // ---- normalize Tv, compute mean(Tv) ----
    if (t < CDIM) {
        const float tv = stv[t];
        float sa = fabsf(tv), st = tv;
        #pragma unroll
        for (int off = 16; off; off >>= 1) {
            sa += __shfl_xor(sa, off);
            st += __shfl_xor(st, off);
        }
        stv[t] = tv / sa;
        if (t == 0) s_mean = (st / sa) * (1.0f / CDIM);
    }
    __syncthreads();

    // ---- Phase B: v_proj[g] = sum_c delta[c][g]*Tv[c] - mean(Tv)*sum_c delta[c][g]
    // 2 threads per g, 16 neighbors each; consecutive lanes read consecutive g (conflict-free).
    {
        const int g = t & (GDIM - 1);
        const int h = t >> 7;  // 0 or 1
        float acc = 0.f, sd = 0.f;
        #pragma unroll
        for (int cc = 0; cc < 16; ++cc) {
            const int c2 = h * 16 + cc;
            const float d = sdel[c2][g];
            acc = fmaf(d, stv[c2], acc);
            sd += d;
        }
        if (h == 1) { s_acc[g] = acc; s_sumd[g] = sd; }
        __syncthreads();
        if (h == 0) {
            const float ta = acc + s_acc[g];
            const float ts = sd  + s_sumd[g];
            out[(size_t)i * GDIM + g] = ta - s_mean * ts;
        }
    }
}

extern "C" void kernel_launch(void* const* d_in, const int* in_sizes, int n_in,
                              void* d_out, int out_size, void* d_ws, size_t ws_size,
                              hipStream_t stream) {
    const float* x = (const float*)d_in[0];
    const float* v = (const float*)d_in[1];
    const int*   k = (const int*)  d_in[2];
    const float* X = (const float*)d_in[3];
    float* out = (float*)d_out;
    const int n = in_sizes[0] / GDIM;  // 16384 rows
    nc_kernel<<<n, 256, 0, stream>>>(x, v, k, X, out);
}

// Round 4
// 179.215 us; speedup vs baseline: 1.0067x; 1.0067x over previous
//
#include <hip/hip_runtime.h>
#include <math.h>

#define GDIM 128
#define CDIM 32
#define EPSV 1e-8f
#define INV_SIGMA 10.0f
#define PAD 4   // row stride 132 floats -> near-conflict-free strided reads

// __launch_bounds__(256, 8): 8 blocks/CU (LDS allows ~9), caps VGPR at 64 so
// the 4 gather float4s (16 VGPRs) stay simultaneously in flight (MLP=4).
__global__ __launch_bounds__(256, 8) void nc_kernel(
    const float* __restrict__ x, const float* __restrict__ v,
    const int*   __restrict__ k, const float* __restrict__ X,
    float* __restrict__ out)
{
    const int i = blockIdx.x;
    const int t = threadIdx.x;

    __shared__ float sdel[CDIM][GDIM + PAD];  // 32 x 132 x 4B = 16.9 KB
    __shared__ float sv[GDIM];
    __shared__ float stv[CDIM];
    __shared__ float s_vnorm;
    __shared__ float s_mean;

    // ---- wave 0: load v row (issue early, overlaps gather) ----
    float va = 0.f, vb = 0.f;
    if (t < 64) {
        va = v[(size_t)i * GDIM + t];
        vb = v[(size_t)i * GDIM + t + 64];
    }

    // ---- gather with explicit 4-deep MLP ----
    // 32 lanes per row (32 x float4 = 512 B coalesced), rows c = (t>>5) + 8r.
    const int lane4 = (t & 31) * 4;
    const int cbase = t >> 5;
    int k0 = k[(size_t)i * CDIM + cbase];
    int k1 = k[(size_t)i * CDIM + cbase + 8];
    int k2 = k[(size_t)i * CDIM + cbase + 16];
    int k3 = k[(size_t)i * CDIM + cbase + 24];
    const float4 xv = *reinterpret_cast<const float4*>(&x[(size_t)i * GDIM + lane4]);
    const float4 X0 = *reinterpret_cast<const float4*>(&X[(size_t)k0 * GDIM + lane4]);
    const float4 X1 = *reinterpret_cast<const float4*>(&X[(size_t)k1 * GDIM + lane4]);
    const float4 X2 = *reinterpret_cast<const float4*>(&X[(size_t)k2 * GDIM + lane4]);
    const float4 X3 = *reinterpret_cast<const float4*>(&X[(size_t)k3 * GDIM + lane4]);

    // ---- wave 0: sv stage + ||v|| while gathers are in flight ----
    if (t < 64) {
        sv[t] = va; sv[t + 64] = vb;
        float vn = va * va + vb * vb;
        #pragma unroll
        for (int off = 32; off; off >>= 1) vn += __shfl_xor(vn, off);
        if (t == 0) s_vnorm = sqrtf(vn);
    }

    // ---- deltas into LDS ----
    {
        float4 d;
        d.x = X0.x - xv.x; d.y = X0.y - xv.y; d.z = X0.z - xv.z; d.w = X0.w - xv.w;
        *reinterpret_cast<float4*>(&sdel[cbase][lane4]) = d;
        d.x = X1.x - xv.x; d.y = X1.y - xv.y; d.z = X1.z - xv.z; d.w = X1.w - xv.w;
        *reinterpret_cast<float4*>(&sdel[cbase + 8][lane4]) = d;
        d.x = X2.x - xv.x; d.y = X2.y - xv.y; d.z = X2.z - xv.z; d.w = X2.w - xv.w;
        *reinterpret_cast<float4*>(&sdel[cbase + 16][lane4]) = d;
        d.x = X3.x - xv.x; d.y = X3.y - xv.y; d.z = X3.z - xv.z; d.w = X3.w - xv.w;
        *reinterpret_cast<float4*>(&sdel[cbase + 24][lane4]) = d;
    }
    __syncthreads();  // B1: deltas, sv, s_vnorm ready

    // ---- Phase A: dot(v,delta) and ||delta||^2, 8 threads per neighbor ----
    {
        const int c = t >> 3;
        const int l = t & 7;
        float num = 0.f, ss = 0.f;
        #pragma unroll
        for (int j = 0; j < 16; ++j) {
            const int g = l + 8 * j;
            const float d = sdel[c][g];
            num = fmaf(sv[g], d, num);
            ss  = fmaf(d, d, ss);
        }
        #pragma unroll
        for (int off = 4; off; off >>= 1) {
            num += __shfl_xor(num, off);
            ss  += __shfl_xor(ss, off);
        }
        if (l == 0) {
            const float dn = sqrtf(ss);
            const float cs = num / fmaxf(s_vnorm * dn, EPSV);
            stv[c] = expm1f(cs * INV_SIGMA);
        }
    }
    __syncthreads();  // B2: raw Tv ready

    // ---- normalize Tv + mean ----
    if (t < CDIM) {
        const float tv = stv[t];
        float sa = fabsf(tv), st = tv;
        #pragma unroll
        for (int off = 16; off; off >>= 1) {
            sa += __shfl_xor(sa, off);
            st += __shfl_xor(st, off);
        }
        stv[t] = tv / sa;
        if (t == 0) s_mean = (st / sa) * (1.0f / CDIM);
    }
    __syncthreads();  // B3: normalized Tv + mean ready

    // ---- Phase B: single-pass, 128 threads, one g each, 32 neighbors ----
    if (t < GDIM) {
        const int g = t;
        float acc = 0.f, sd = 0.f;
        #pragma unroll
        for (int c = 0; c < CDIM; ++c) {
            const float d = sdel[c][g];
            acc = fmaf(d, stv[c], acc);  // stv[c] is a same-address broadcast read
            sd += d;
        }
        out[(size_t)i * GDIM + g] = acc - s_mean * sd;
    }
}

extern "C" void kernel_launch(void* const* d_in, const int* in_sizes, int n_in,
                              void* d_out, int out_size, void* d_ws, size_t ws_size,
                              hipStream_t stream) {
    const float* x = (const float*)d_in[0];
    const float* v = (const float*)d_in[1];
    const int*   k = (const int*)  d_in[2];
    const float* X = (const float*)d_in[3];
    float* out = (float*)d_out;
    const int n = in_sizes[0] / GDIM;  // 16384 rows
    nc_kernel<<<n, 256, 0, stream>>>(x, v, k, X, out);
}